// Round 2
// baseline (1962.071 us; speedup 1.0000x reference)
//
#include <hip/hip_runtime.h>

typedef __fp16 half2_t __attribute__((ext_vector_type(2)));

#define NB 128
#define TT 2048
#define DD 256

static __device__ __forceinline__ float fdot2(half2_t a, half2_t b, float c) {
#if __has_builtin(__builtin_amdgcn_fdot2)
  return __builtin_amdgcn_fdot2(a, b, c, false);
#else
  return c + (float)a[0] * (float)b[0] + (float)a[1] * (float)b[1];
#endif
}

static __device__ __forceinline__ float fast_tanh(float y) {
  // tanh(y) = 1 - 2/(exp(2y)+1); exp via exp2
  float e = __builtin_expf(y * 2.0f);
  return 1.0f - 2.0f / (e + 1.0f);
}

// One block per batch row. 512 threads = 8 waves.
// Thread (wid, lane): jj = wid*32 + (lane&31)  -> output dim j in [0,256)
//                     half = lane>>5           -> k-range [half*128, half*128+128)
// Lam row jj (k-half) and B row jj (k-half) live in VGPRs as 64+64 packed f16x2.
// h and x_t live in LDS as 128+128 dwords of packed f16x2, rewritten every step.
__global__ __launch_bounds__(512, 2) void rnn_fused_scan(
    const float* __restrict__ X, const float* __restrict__ Bm,
    const float* __restrict__ Lm, float* __restrict__ out)
{
  const int b    = blockIdx.x;
  const int tid  = threadIdx.x;
  const int wid  = tid >> 6;
  const int lane = tid & 63;
  const int jj   = (wid << 5) | (lane & 31);
  const int half = lane >> 5;

  __shared__ __align__(16) unsigned int hbuf[DD / 2];
  __shared__ __align__(16) unsigned int xbuf[DD / 2];

  // ---- one-time: stage Lam/B rows into registers as f16 pairs ----
  half2_t lam[64], bb[64];
  {
    const float4* lp = (const float4*)(Lm + jj * DD + half * 128);
    const float4* bp = (const float4*)(Bm + jj * DD + half * 128);
#pragma unroll
    for (int u = 0; u < 32; ++u) {
      float4 lv = lp[u];
      float4 bv = bp[u];
      lam[2*u]   = __builtin_amdgcn_cvt_pkrtz(lv.x, lv.y);
      lam[2*u+1] = __builtin_amdgcn_cvt_pkrtz(lv.z, lv.w);
      bb[2*u]    = __builtin_amdgcn_cvt_pkrtz(bv.x, bv.y);
      bb[2*u+1]  = __builtin_amdgcn_cvt_pkrtz(bv.z, bv.w);
    }
  }

  const float* xrow = X + (size_t)b * (TT * DD);
  float* orow = out + (size_t)b * (TT * DD) + jj;

  // ---- prologue: h0 = 0, xbuf = x[0], prefetch x[1..4] into registers ----
  float2 xp0 = {0.f, 0.f}, xp1 = {0.f, 0.f}, xp2 = {0.f, 0.f}, xp3 = {0.f, 0.f};
  if (tid < 128) {
    hbuf[tid] = 0u;
    float2 x0 = *(const float2*)(xrow + 2 * tid);
    xbuf[tid] = __builtin_bit_cast(unsigned int,
                                   __builtin_amdgcn_cvt_pkrtz(x0.x, x0.y));
    xp0 = *(const float2*)(xrow + 1 * DD + 2 * tid);
    xp1 = *(const float2*)(xrow + 2 * DD + 2 * tid);
    xp2 = *(const float2*)(xrow + 3 * DD + 2 * tid);
    xp3 = *(const float2*)(xrow + 4 * DD + 2 * tid);
  }
  __syncthreads();

  const unsigned int* hb = hbuf + half * 64;
  const unsigned int* xb = xbuf + half * 64;

  // Raw s_barrier + lgkmcnt-only drains: global prefetch loads / out stores
  // stay in flight across the barriers (a plain __syncthreads would drain
  // vmcnt(0) and serialize ~900cy HBM latency into every step).
#define STEP(t, xp)                                                            \
  {                                                                            \
    float a0=0.f,a1=0.f,a2=0.f,a3=0.f,c0=0.f,c1=0.f,c2=0.f,c3=0.f;             \
    _Pragma("unroll")                                                          \
    for (int u = 0; u < 16; ++u) {                                             \
      uint4 hv = *(const uint4*)(hb + 4*u);                                    \
      uint4 xv = *(const uint4*)(xb + 4*u);                                    \
      a0 = fdot2(lam[4*u+0], __builtin_bit_cast(half2_t, hv.x), a0);           \
      a1 = fdot2(lam[4*u+1], __builtin_bit_cast(half2_t, hv.y), a1);           \
      a2 = fdot2(lam[4*u+2], __builtin_bit_cast(half2_t, hv.z), a2);           \
      a3 = fdot2(lam[4*u+3], __builtin_bit_cast(half2_t, hv.w), a3);           \
      c0 = fdot2(bb[4*u+0],  __builtin_bit_cast(half2_t, xv.x), c0);           \
      c1 = fdot2(bb[4*u+1],  __builtin_bit_cast(half2_t, xv.y), c1);           \
      c2 = fdot2(bb[4*u+2],  __builtin_bit_cast(half2_t, xv.z), c2);           \
      c3 = fdot2(bb[4*u+3],  __builtin_bit_cast(half2_t, xv.w), c3);           \
    }                                                                          \
    float pre = ((a0+a1)+(a2+a3)) + ((c0+c1)+(c2+c3));                         \
    pre += __shfl_xor(pre, 32);                                                \
    float hn = fast_tanh(pre);                                                 \
    if (half == 0) orow[(t) * DD] = hn;                                        \
    asm volatile("s_waitcnt lgkmcnt(0)" ::: "memory");                         \
    __builtin_amdgcn_s_barrier();  /* reads of h/x done everywhere */          \
    if (half == 1) ((__fp16*)hbuf)[jj] = (__fp16)hn;                           \
    if (tid < 128) {                                                           \
      xbuf[tid] = __builtin_bit_cast(unsigned int,                             \
                    __builtin_amdgcn_cvt_pkrtz(xp.x, xp.y));                   \
      int tn = (t) + 5; tn = tn > TT - 1 ? TT - 1 : tn;                        \
      xp = *(const float2*)(xrow + tn * DD + 2 * tid);                         \
    }                                                                          \
    asm volatile("s_waitcnt lgkmcnt(0)" ::: "memory");                         \
    __builtin_amdgcn_s_barrier();  /* new h/x visible everywhere */            \
  }

  // Step loop unrolled x4 so the x-prefetch register pipeline has static
  // slot indices (runtime-indexed register arrays would go to scratch).
  for (int t = 0; t < TT; t += 4) {
    STEP(t + 0, xp0)
    STEP(t + 1, xp1)
    STEP(t + 2, xp2)
    STEP(t + 3, xp3)
  }
#undef STEP
}

extern "C" void kernel_launch(void* const* d_in, const int* in_sizes, int n_in,
                              void* d_out, int out_size, void* d_ws, size_t ws_size,
                              hipStream_t stream) {
  const float* X  = (const float*)d_in[0];   // [128, 2048, 256] f32
  const float* Bm = (const float*)d_in[1];   // [256, 256] f32
  const float* Lm = (const float*)d_in[2];   // [256, 256] f32
  float* out = (float*)d_out;                // [128, 2048, 256] f32
  hipLaunchKernelGGL(rnn_fused_scan, dim3(NB), dim3(512), 0, stream,
                     X, Bm, Lm, out);
}

// Round 3
// 1808.851 us; speedup vs baseline: 1.0847x; 1.0847x over previous
//
#include <hip/hip_runtime.h>

typedef __fp16 half2_t __attribute__((ext_vector_type(2)));

#define NB 128
#define TT 2048
#define DD 256

static __device__ __forceinline__ float fdot2(half2_t a, half2_t b, float c) {
#if __has_builtin(__builtin_amdgcn_fdot2)
  return __builtin_amdgcn_fdot2(a, b, c, false);
#else
  return c + (float)a[0] * (float)b[0] + (float)a[1] * (float)b[1];
#endif
}

static __device__ __forceinline__ float fast_tanh(float y) {
  float e = __builtin_expf(y * 2.0f);
  return 1.0f - 2.0f / (e + 1.0f);
}

// Cross-lane helpers: xor1/xor2 via DPP quad_perm (VALU pipe, no LDS traffic),
// xor4/xor8 via ds_swizzle (LDS pipe, only 2 per thread per step).
static __device__ __forceinline__ float dpp_xor1(float v) {
  return __builtin_bit_cast(float, __builtin_amdgcn_update_dpp(
      0, __builtin_bit_cast(int, v), 0xB1 /*quad_perm 1,0,3,2*/, 0xF, 0xF, true));
}
static __device__ __forceinline__ float dpp_xor2(float v) {
  return __builtin_bit_cast(float, __builtin_amdgcn_update_dpp(
      0, __builtin_bit_cast(int, v), 0x4E /*quad_perm 2,3,0,1*/, 0xF, 0xF, true));
}
static __device__ __forceinline__ float swz_xor4(float v) {
  return __builtin_bit_cast(float, __builtin_amdgcn_ds_swizzle(
      __builtin_bit_cast(int, v), (4 << 10) | 0x1F));
}
static __device__ __forceinline__ float swz_xor8(float v) {
  return __builtin_bit_cast(float, __builtin_amdgcn_ds_swizzle(
      __builtin_bit_cast(int, v), (8 << 10) | 0x1F));
}

// One block per batch row. 512 threads = 8 waves.
// Lane split: group g = lane>>4 (4 per wave), sublane s = lane&15.
// Group G = wid*4+g owns output rows j in [G*8, G*8+8); sublane s owns
// k-chunk [s*16, s*16+16). Each thread holds 8x16 f16 weights of BOTH
// Lam and B (128 VGPRs total) -> LDS broadcast traffic is 64 B/thread/step
// (8x less than the J=1 layout), reduction over 16 sublanes is a
// responsibility-splitting butterfly: 8 shuffles (4+2 DPP, 2 swizzle).
__global__ __launch_bounds__(512, 2) void rnn_fused_scan(
    const float* __restrict__ X, const float* __restrict__ Bm,
    const float* __restrict__ Lm, float* __restrict__ out)
{
  const int b    = blockIdx.x;
  const int tid  = threadIdx.x;
  const int wid  = tid >> 6;
  const int lane = tid & 63;
  const int g    = lane >> 4;
  const int s    = lane & 15;
  const int G    = (wid << 2) | g;
  const int jbase = G << 3;
  const int k0   = s << 4;

  const bool s1b = (s & 1) != 0;
  const bool s2b = (s & 2) != 0;
  const bool s4b = (s & 4) != 0;
  const bool wr  = (s < 8);
  const int  rmap = ((s & 1) << 2) | (s & 2) | ((s >> 2) & 1);
  const int  j_out = jbase + rmap;

  __shared__ __align__(16) unsigned int hbuf[DD / 2];
  __shared__ __align__(16) unsigned int xbuf[DD / 2];

  // ---- one-time: stage 8 rows x 16 k of Lam and B into registers (f16x2) ----
  half2_t lamw[64], bw[64];
#pragma unroll
  for (int r = 0; r < 8; ++r) {
    const float4* lp = (const float4*)(Lm + (jbase + r) * DD + k0);
    const float4* bp = (const float4*)(Bm + (jbase + r) * DD + k0);
#pragma unroll
    for (int q = 0; q < 4; ++q) {
      float4 lv = lp[q];
      float4 bv = bp[q];
      lamw[r * 8 + 2 * q]     = __builtin_amdgcn_cvt_pkrtz(lv.x, lv.y);
      lamw[r * 8 + 2 * q + 1] = __builtin_amdgcn_cvt_pkrtz(lv.z, lv.w);
      bw[r * 8 + 2 * q]       = __builtin_amdgcn_cvt_pkrtz(bv.x, bv.y);
      bw[r * 8 + 2 * q + 1]   = __builtin_amdgcn_cvt_pkrtz(bv.z, bv.w);
    }
  }

  const float* xrow = X + (size_t)b * (TT * DD);
  float* orow_j = out + (size_t)b * (TT * DD) + j_out;

  // ---- prologue: h0 = 0, xbuf = x[0], prefetch x[1..4] into registers ----
  float2 xp0 = {0.f, 0.f}, xp1 = {0.f, 0.f}, xp2 = {0.f, 0.f}, xp3 = {0.f, 0.f};
  if (tid < 128) {
    hbuf[tid] = 0u;
    float2 x0 = *(const float2*)(xrow + 2 * tid);
    xbuf[tid] = __builtin_bit_cast(unsigned int,
                                   __builtin_amdgcn_cvt_pkrtz(x0.x, x0.y));
    xp0 = *(const float2*)(xrow + 1 * DD + 2 * tid);
    xp1 = *(const float2*)(xrow + 2 * DD + 2 * tid);
    xp2 = *(const float2*)(xrow + 3 * DD + 2 * tid);
    xp3 = *(const float2*)(xrow + 4 * DD + 2 * tid);
  }
  __syncthreads();

  // Raw s_barrier + lgkmcnt-only drains: global prefetch loads / out stores
  // stay in flight across the barriers (plain __syncthreads would drain
  // vmcnt(0) and serialize HBM latency into every step).
#define STEP(t, xp)                                                            \
  {                                                                            \
    const uint4* hq = (const uint4*)(hbuf + (s << 3));                         \
    const uint4* xq = (const uint4*)(xbuf + (s << 3));                         \
    uint4 h0v = hq[0], h1v = hq[1], x0v = xq[0], x1v = xq[1];                  \
    unsigned int hd[8] = {h0v.x, h0v.y, h0v.z, h0v.w,                          \
                          h1v.x, h1v.y, h1v.z, h1v.w};                         \
    unsigned int xd[8] = {x0v.x, x0v.y, x0v.z, x0v.w,                          \
                          x1v.x, x1v.y, x1v.z, x1v.w};                         \
    float acc[8];                                                              \
    _Pragma("unroll")                                                          \
    for (int r = 0; r < 8; ++r) {                                              \
      float a = 0.f;                                                           \
      _Pragma("unroll")                                                        \
      for (int q = 0; q < 8; ++q) {                                            \
        a = fdot2(lamw[r * 8 + q], __builtin_bit_cast(half2_t, hd[q]), a);     \
        a = fdot2(bw[r * 8 + q],  __builtin_bit_cast(half2_t, xd[q]), a);      \
      }                                                                        \
      acc[r] = a;                                                              \
    }                                                                          \
    /* stage 1 (xor1): even sublanes keep r 0..3, odd keep 4..7 */             \
    float t0 = s1b ? acc[0] : acc[4], u0 = s1b ? acc[4] : acc[0];              \
    float t1 = s1b ? acc[1] : acc[5], u1 = s1b ? acc[5] : acc[1];              \
    float t2 = s1b ? acc[2] : acc[6], u2 = s1b ? acc[6] : acc[2];              \
    float t3 = s1b ? acc[3] : acc[7], u3 = s1b ? acc[7] : acc[3];              \
    float b0 = u0 + dpp_xor1(t0);                                              \
    float b1 = u1 + dpp_xor1(t1);                                              \
    float b2 = u2 + dpp_xor1(t2);                                              \
    float b3 = u3 + dpp_xor1(t3);                                              \
    /* stage 2 (xor2) */                                                       \
    float v0 = s2b ? b0 : b2, w0 = s2b ? b2 : b0;                              \
    float v1 = s2b ? b1 : b3, w1 = s2b ? b3 : b1;                              \
    float c0 = w0 + dpp_xor2(v0);                                              \
    float c1 = w1 + dpp_xor2(v1);                                              \
    /* stage 3 (xor4) */                                                       \
    float v2 = s4b ? c0 : c1, w2 = s4b ? c1 : c0;                              \
    float d_ = w2 + swz_xor4(v2);                                              \
    /* stage 4 (xor8): both copies sum */                                      \
    float pre = d_ + swz_xor8(d_);                                             \
    float hn = fast_tanh(pre);                                                 \
    if (wr) orow_j[(t) * DD] = hn;                                             \
    asm volatile("s_waitcnt lgkmcnt(0)" ::: "memory");                         \
    __builtin_amdgcn_s_barrier(); /* all reads of h/x done everywhere */       \
    if (wr) ((__fp16*)hbuf)[j_out] = (__fp16)hn;                               \
    if (tid < 128) {                                                           \
      xbuf[tid] = __builtin_bit_cast(unsigned int,                             \
                    __builtin_amdgcn_cvt_pkrtz(xp.x, xp.y));                   \
      int tn = (t) + 5; tn = tn > TT - 1 ? TT - 1 : tn;                        \
      xp = *(const float2*)(xrow + tn * DD + 2 * tid);                         \
    }                                                                          \
    asm volatile("s_waitcnt lgkmcnt(0)" ::: "memory");                         \
    __builtin_amdgcn_s_barrier(); /* new h/x visible everywhere */             \
  }

  // Step loop unrolled x4 so the x-prefetch register pipeline has static
  // slot indices (runtime-indexed register arrays would go to scratch).
  for (int t = 0; t < TT; t += 4) {
    STEP(t + 0, xp0)
    STEP(t + 1, xp1)
    STEP(t + 2, xp2)
    STEP(t + 3, xp3)
  }
#undef STEP
}

extern "C" void kernel_launch(void* const* d_in, const int* in_sizes, int n_in,
                              void* d_out, int out_size, void* d_ws, size_t ws_size,
                              hipStream_t stream) {
  const float* X  = (const float*)d_in[0];   // [128, 2048, 256] f32
  const float* Bm = (const float*)d_in[1];   // [256, 256] f32
  const float* Lm = (const float*)d_in[2];   // [256, 256] f32
  float* out = (float*)d_out;                // [128, 2048, 256] f32
  hipLaunchKernelGGL(rnn_fused_scan, dim3(NB), dim3(512), 0, stream,
                     X, Bm, Lm, out);
}

// Round 4
// 1382.423 us; speedup vs baseline: 1.4193x; 1.3085x over previous
//
#include <hip/hip_runtime.h>

#define TT 2048
#define DD 256

typedef __fp16 half2_t __attribute__((ext_vector_type(2)));
typedef __fp16 half8_t __attribute__((ext_vector_type(8)));
typedef float f32x4_t __attribute__((ext_vector_type(4)));

static __device__ __forceinline__ float fdot2(half2_t a, half2_t b, float c) {
  return __builtin_amdgcn_fdot2(a, b, c, false);
}

static __device__ __forceinline__ float fast_tanh(float y) {
  float e = __builtin_expf(y * 2.0f);
  return 1.0f - 2.0f / (e + 1.0f);
}

static __device__ __forceinline__ float dpp_xor1(float v) {
  return __builtin_bit_cast(float, __builtin_amdgcn_update_dpp(
      0, __builtin_bit_cast(int, v), 0xB1 /*quad_perm 1,0,3,2*/, 0xF, 0xF, true));
}
static __device__ __forceinline__ float dpp_xor2(float v) {
  return __builtin_bit_cast(float, __builtin_amdgcn_update_dpp(
      0, __builtin_bit_cast(int, v), 0x4E /*quad_perm 2,3,0,1*/, 0xF, 0xF, true));
}
static __device__ __forceinline__ float swz_xor4(float v) {
  return __builtin_bit_cast(float, __builtin_amdgcn_ds_swizzle(
      __builtin_bit_cast(int, v), (4 << 10) | 0x1F));
}

// ---------------- Phase 1: U = X * B^T  (MFMA), U written into d_out ----------
// Block: 256 thr = 4 waves; wave does 32 tokens x 256 cols, K=256.
// B staged in LDS as f16 [256][264] (pad 264 -> row stride 528B == 4 banks rot,
// spreads the 16-rows-per-col-slice frag reads to the b128 baseline pattern).
#define BST 264
__global__ __launch_bounds__(256, 1) void rnn_u_gemm(
    const float* __restrict__ X, const float* __restrict__ Bm,
    float* __restrict__ U)
{
  extern __shared__ __fp16 bsh[];  // [256][BST]
  const int tid = threadIdx.x;

  { // stage B: one row per thread, f32 -> f16
    const float* br = Bm + tid * DD;
    __fp16* dst = bsh + tid * BST;
#pragma unroll
    for (int c = 0; c < 32; ++c) {
      float4 v0 = *(const float4*)(br + c * 8);
      float4 v1 = *(const float4*)(br + c * 8 + 4);
      uint4 w;
      w.x = __builtin_bit_cast(unsigned int, __builtin_amdgcn_cvt_pkrtz(v0.x, v0.y));
      w.y = __builtin_bit_cast(unsigned int, __builtin_amdgcn_cvt_pkrtz(v0.z, v0.w));
      w.z = __builtin_bit_cast(unsigned int, __builtin_amdgcn_cvt_pkrtz(v1.x, v1.y));
      w.w = __builtin_bit_cast(unsigned int, __builtin_amdgcn_cvt_pkrtz(v1.z, v1.w));
      *(uint4*)(dst + c * 8) = w;
    }
  }
  __syncthreads();

  const int wv = tid >> 6;
  const int l = tid & 63;
  const int l16 = l & 15;
  const int lk = l >> 4;
  const size_t tok0 = (size_t)blockIdx.x * 128 + wv * 32;

  f32x4_t acc[2][16];
#pragma unroll
  for (int m = 0; m < 2; ++m)
#pragma unroll
    for (int n = 0; n < 16; ++n)
      acc[m][n] = (f32x4_t){0.f, 0.f, 0.f, 0.f};

  const float* xA0 = X + (tok0 + l16) * DD + lk * 8;
  const float* xA1 = X + (tok0 + 16 + l16) * DD + lk * 8;

#pragma unroll
  for (int ks = 0; ks < 8; ++ks) {
    float4 a00 = *(const float4*)(xA0 + ks * 32);
    float4 a01 = *(const float4*)(xA0 + ks * 32 + 4);
    float4 a10 = *(const float4*)(xA1 + ks * 32);
    float4 a11 = *(const float4*)(xA1 + ks * 32 + 4);
    half2_t p0 = __builtin_amdgcn_cvt_pkrtz(a00.x, a00.y);
    half2_t p1 = __builtin_amdgcn_cvt_pkrtz(a00.z, a00.w);
    half2_t p2 = __builtin_amdgcn_cvt_pkrtz(a01.x, a01.y);
    half2_t p3 = __builtin_amdgcn_cvt_pkrtz(a01.z, a01.w);
    half2_t r0 = __builtin_amdgcn_cvt_pkrtz(a10.x, a10.y);
    half2_t r1 = __builtin_amdgcn_cvt_pkrtz(a10.z, a10.w);
    half2_t r2 = __builtin_amdgcn_cvt_pkrtz(a11.x, a11.y);
    half2_t r3 = __builtin_amdgcn_cvt_pkrtz(a11.z, a11.w);
    half8_t af0 = {p0[0], p0[1], p1[0], p1[1], p2[0], p2[1], p3[0], p3[1]};
    half8_t af1 = {r0[0], r0[1], r1[0], r1[1], r2[0], r2[1], r3[0], r3[1]};
#pragma unroll
    for (int n = 0; n < 16; ++n) {
      half8_t bf = *(const half8_t*)(bsh + (n * 16 + l16) * BST + ks * 32 + lk * 8);
      acc[0][n] = __builtin_amdgcn_mfma_f32_16x16x32_f16(af0, bf, acc[0][n], 0, 0, 0);
      acc[1][n] = __builtin_amdgcn_mfma_f32_16x16x32_f16(af1, bf, acc[1][n], 0, 0, 0);
    }
  }

  // D layout: col = l&15, row = (l>>4)*4 + r  (m89-verified, dtype-independent)
#pragma unroll
  for (int m = 0; m < 2; ++m) {
    float* ub = U + (tok0 + m * 16 + lk * 4) * DD + l16;
#pragma unroll
    for (int n = 0; n < 16; ++n)
#pragma unroll
      for (int r = 0; r < 4; ++r)
        ub[(size_t)r * DD + n * 16] = acc[m][n][r];
  }
}

// ---------------- Phase 2: sequential scan h_t = tanh(U_t + Lam h_{t-1}) -----
// One block per batch row; 512 thr = 8 waves. Group G = wid*8 + (lane>>3)
// owns rows [G*4, G*4+4); sublane s = lane&7 owns k-chunk [s*32, s*32+32).
// Lam weights (4 rows x 32 k, f16x2 = 64 VGPR) stay in registers.
// h double-buffered in LDS (one barrier/step), quad-XOR swizzled (2-way max).
// Reduce over 8 sublanes: xor1+xor2 via DPP (VALU pipe) + one ds_swizzle xor4.
__global__ __launch_bounds__(512, 1) void rnn_scan(
    const float* __restrict__ Lm, float* outp /* U in, h out */)
{
  const int b = blockIdx.x;
  const int tid = threadIdx.x;
  const int wid = tid >> 6;
  const int lane = tid & 63;
  const int g = lane >> 3;
  const int s = lane & 7;
  const int s3 = s & 3;
  const int G = (wid << 3) | g;
  const int jbase = G << 2;
  const int rmap = ((s & 1) << 1) | ((s & 2) >> 1);
  const int j_out = jbase + rmap;
  const bool wr = (s < 4);
  const bool s1b = (s & 1) != 0;
  const bool s2b = (s & 2) != 0;

  __shared__ __align__(16) __fp16 hbuf[2][DD];

  // weights: 4 rows x 16 f16x2 regs; reg idx j <-> k-pair s*32 + 2*j
  half2_t lamw[4][16];
#pragma unroll
  for (int r = 0; r < 4; ++r) {
    const float* lp = Lm + (jbase + r) * DD + s * 32;
#pragma unroll
    for (int q = 0; q < 8; ++q) {
      float4 v = *(const float4*)(lp + q * 4);
      lamw[r][2 * q]     = __builtin_amdgcn_cvt_pkrtz(v.x, v.y);
      lamw[r][2 * q + 1] = __builtin_amdgcn_cvt_pkrtz(v.z, v.w);
    }
  }

  // h read: chunk s, quad slot (q ^ s3) holds original quad q (bank swizzle)
  const __fp16* hb0 = &hbuf[0][s * 32];
  const __fp16* hb1 = &hbuf[1][s * 32];
  const int o0 = 8 * (0 ^ s3), o1 = 8 * (1 ^ s3);
  const int o2 = 8 * (2 ^ s3), o3 = 8 * (3 ^ s3);
  // h write position for j_out under the same swizzle
  const int posj = (j_out & ~24) | ((((j_out >> 3) & 3) ^ ((j_out >> 5) & 3)) << 3);
  __fp16* hw0p = &hbuf[0][posj];
  __fp16* hw1p = &hbuf[1][posj];

  const size_t obase = (size_t)b * (TT * DD) + j_out;

  // prologue: h0 = 0 in hbuf[0]; U[0..3] register pipeline
  if (tid < 128) ((unsigned int*)hbuf)[tid] = 0u;
  float up0 = outp[obase + 0 * DD];
  float up1 = outp[obase + 1 * DD];
  float up2 = outp[obase + 2 * DD];
  float up3 = outp[obase + 3 * DD];
  __syncthreads();

  // Raw s_barrier + lgkmcnt-only drain: the U prefetch loads and out stores
  // stay in flight across the barrier (vmcnt never drained in-loop).
#define STEP(t, up, p)                                                         \
  {                                                                            \
    const __fp16* hbp = (p) ? hb1 : hb0;                                       \
    uint4 hv0 = *(const uint4*)(hbp + o0);                                     \
    uint4 hv1 = *(const uint4*)(hbp + o1);                                     \
    uint4 hv2 = *(const uint4*)(hbp + o2);                                     \
    uint4 hv3 = *(const uint4*)(hbp + o3);                                     \
    unsigned int hw[16] = {hv0.x, hv0.y, hv0.z, hv0.w,                         \
                           hv1.x, hv1.y, hv1.z, hv1.w,                         \
                           hv2.x, hv2.y, hv2.z, hv2.w,                         \
                           hv3.x, hv3.y, hv3.z, hv3.w};                        \
    float accv[4];                                                             \
    _Pragma("unroll")                                                          \
    for (int r = 0; r < 4; ++r) {                                              \
      float A = 0.f, Bc = 0.f;                                                 \
      _Pragma("unroll")                                                        \
      for (int w2 = 0; w2 < 8; ++w2) {                                         \
        A  = fdot2(lamw[r][2 * w2],     __builtin_bit_cast(half2_t, hw[2 * w2]),     A);  \
        Bc = fdot2(lamw[r][2 * w2 + 1], __builtin_bit_cast(half2_t, hw[2 * w2 + 1]), Bc); \
      }                                                                        \
      accv[r] = A + Bc;                                                        \
    }                                                                          \
    /* stage 1 (xor1, DPP): even s keep rows {0,1}, odd keep {2,3} */          \
    float t0 = s1b ? accv[0] : accv[2], u0 = s1b ? accv[2] : accv[0];          \
    float t1 = s1b ? accv[1] : accv[3], u1 = s1b ? accv[3] : accv[1];          \
    float b0 = u0 + dpp_xor1(t0);                                              \
    float b1 = u1 + dpp_xor1(t1);                                              \
    /* stage 2 (xor2, DPP): keep one row = jbase + rmap */                     \
    float v0 = s2b ? b0 : b1, w0 = s2b ? b1 : b0;                              \
    float c0 = w0 + dpp_xor2(v0);                                              \
    /* stage 3 (xor4, one LDS-pipe swizzle) + U + tanh */                      \
    float pre = c0 + swz_xor4(c0) + (up);                                      \
    float hn = fast_tanh(pre);                                                 \
    if (wr) {                                                                  \
      outp[obase + (size_t)(t) * DD] = hn;                                     \
      *((p) ? hw0p : hw1p) = (__fp16)hn;  /* write parity p^1 */               \
    }                                                                          \
    { int tn = (t) + 4; tn = tn > TT - 1 ? TT - 1 : tn;                        \
      up = outp[obase + (size_t)tn * DD]; }                                    \
    asm volatile("s_waitcnt lgkmcnt(0)" ::: "memory");                         \
    __builtin_amdgcn_s_barrier();                                              \
    asm volatile("" ::: "memory");                                             \
  }

  for (int t = 0; t < TT; t += 4) {
    STEP(t + 0, up0, 0)
    STEP(t + 1, up1, 1)
    STEP(t + 2, up2, 0)
    STEP(t + 3, up3, 1)
  }
#undef STEP
}

extern "C" void kernel_launch(void* const* d_in, const int* in_sizes, int n_in,
                              void* d_out, int out_size, void* d_ws, size_t ws_size,
                              hipStream_t stream) {
  const float* X  = (const float*)d_in[0];   // [128, 2048, 256] f32
  const float* Bm = (const float*)d_in[1];   // [256, 256] f32
  const float* Lm = (const float*)d_in[2];   // [256, 256] f32
  float* out = (float*)d_out;                // [128, 2048, 256] f32

  // Phase 1 needs 135168 B dynamic LDS (> 64 KB default) — opt in (idempotent).
  (void)hipFuncSetAttribute((const void*)rnn_u_gemm,
                            hipFuncAttributeMaxDynamicSharedMemorySize,
                            256 * BST * 2);
  hipLaunchKernelGGL(rnn_u_gemm, dim3(2048), dim3(256), 256 * BST * 2, stream,
                     X, Bm, out);
  hipLaunchKernelGGL(rnn_scan, dim3(128), dim3(512), 0, stream, Lm, out);
}

// Round 5
// 1151.261 us; speedup vs baseline: 1.7043x; 1.2008x over previous
//
#include <hip/hip_runtime.h>

#define TT 2048
#define DD 256

typedef __fp16 half2_t __attribute__((ext_vector_type(2)));
typedef __fp16 half8_t __attribute__((ext_vector_type(8)));
typedef float f32x4_t __attribute__((ext_vector_type(4)));

static __device__ __forceinline__ float fdot2(half2_t a, half2_t b, float c) {
  return __builtin_amdgcn_fdot2(a, b, c, false);
}

// 2 HW instructions (v_exp_f32 + v_rcp_f32). Plain expf/division under -O3
// (no -ffast-math) lowers to a ~50-instr libm polynomial + full div sequence
// sitting inside the serial recurrence chain.
static __device__ __forceinline__ float fast_tanh(float y) {
  float e = __builtin_amdgcn_exp2f(y * 2.885390081777927f);  // exp(2y)
  return 1.0f - 2.0f * __builtin_amdgcn_rcpf(e + 1.0f);
}

// All-DPP butterfly pieces (VALU pipe, no LDS traffic):
static __device__ __forceinline__ float dpp_xor1(float v) {
  return __builtin_bit_cast(float, __builtin_amdgcn_update_dpp(
      0, __builtin_bit_cast(int, v), 0xB1 /*quad_perm 1,0,3,2*/, 0xF, 0xF, true));
}
static __device__ __forceinline__ float dpp_xor2(float v) {
  return __builtin_bit_cast(float, __builtin_amdgcn_update_dpp(
      0, __builtin_bit_cast(int, v), 0x4E /*quad_perm 2,3,0,1*/, 0xF, 0xF, true));
}
static __device__ __forceinline__ float dpp_xor8(float v) {
  // row_ror:8 within a 16-lane row: i -> (i+8)&15 == i^8
  return __builtin_bit_cast(float, __builtin_amdgcn_update_dpp(
      0, __builtin_bit_cast(int, v), 0x128 /*row_ror:8*/, 0xF, 0xF, true));
}

// ---------------- Phase 1: U = X * B^T  (MFMA), U written into d_out ----------
#define BST 264
__global__ __launch_bounds__(256, 1) void rnn_u_gemm(
    const float* __restrict__ X, const float* __restrict__ Bm,
    float* __restrict__ U)
{
  extern __shared__ __fp16 bsh[];  // [256][BST]
  const int tid = threadIdx.x;

  { // stage B: one row per thread, f32 -> f16
    const float* br = Bm + tid * DD;
    __fp16* dst = bsh + tid * BST;
#pragma unroll
    for (int c = 0; c < 32; ++c) {
      float4 v0 = *(const float4*)(br + c * 8);
      float4 v1 = *(const float4*)(br + c * 8 + 4);
      uint4 w;
      w.x = __builtin_bit_cast(unsigned int, __builtin_amdgcn_cvt_pkrtz(v0.x, v0.y));
      w.y = __builtin_bit_cast(unsigned int, __builtin_amdgcn_cvt_pkrtz(v0.z, v0.w));
      w.z = __builtin_bit_cast(unsigned int, __builtin_amdgcn_cvt_pkrtz(v1.x, v1.y));
      w.w = __builtin_bit_cast(unsigned int, __builtin_amdgcn_cvt_pkrtz(v1.z, v1.w));
      *(uint4*)(dst + c * 8) = w;
    }
  }
  __syncthreads();

  const int wv = tid >> 6;
  const int l = tid & 63;
  const int l16 = l & 15;
  const int lk = l >> 4;
  const size_t tok0 = (size_t)blockIdx.x * 128 + wv * 32;

  f32x4_t acc[2][16];
#pragma unroll
  for (int m = 0; m < 2; ++m)
#pragma unroll
    for (int n = 0; n < 16; ++n)
      acc[m][n] = (f32x4_t){0.f, 0.f, 0.f, 0.f};

  const float* xA0 = X + (tok0 + l16) * DD + lk * 8;
  const float* xA1 = X + (tok0 + 16 + l16) * DD + lk * 8;

#pragma unroll
  for (int ks = 0; ks < 8; ++ks) {
    float4 a00 = *(const float4*)(xA0 + ks * 32);
    float4 a01 = *(const float4*)(xA0 + ks * 32 + 4);
    float4 a10 = *(const float4*)(xA1 + ks * 32);
    float4 a11 = *(const float4*)(xA1 + ks * 32 + 4);
    half2_t p0 = __builtin_amdgcn_cvt_pkrtz(a00.x, a00.y);
    half2_t p1 = __builtin_amdgcn_cvt_pkrtz(a00.z, a00.w);
    half2_t p2 = __builtin_amdgcn_cvt_pkrtz(a01.x, a01.y);
    half2_t p3 = __builtin_amdgcn_cvt_pkrtz(a01.z, a01.w);
    half2_t r0 = __builtin_amdgcn_cvt_pkrtz(a10.x, a10.y);
    half2_t r1 = __builtin_amdgcn_cvt_pkrtz(a10.z, a10.w);
    half2_t r2 = __builtin_amdgcn_cvt_pkrtz(a11.x, a11.y);
    half2_t r3 = __builtin_amdgcn_cvt_pkrtz(a11.z, a11.w);
    half8_t af0 = {p0[0], p0[1], p1[0], p1[1], p2[0], p2[1], p3[0], p3[1]};
    half8_t af1 = {r0[0], r0[1], r1[0], r1[1], r2[0], r2[1], r3[0], r3[1]};
#pragma unroll
    for (int n = 0; n < 16; ++n) {
      half8_t bf = *(const half8_t*)(bsh + (n * 16 + l16) * BST + ks * 32 + lk * 8);
      acc[0][n] = __builtin_amdgcn_mfma_f32_16x16x32_f16(af0, bf, acc[0][n], 0, 0, 0);
      acc[1][n] = __builtin_amdgcn_mfma_f32_16x16x32_f16(af1, bf, acc[1][n], 0, 0, 0);
    }
  }

  // D layout: col = l&15, row = (l>>4)*4 + r
#pragma unroll
  for (int m = 0; m < 2; ++m) {
    float* ub = U + (tok0 + m * 16 + lk * 4) * DD + l16;
#pragma unroll
    for (int n = 0; n < 16; ++n)
#pragma unroll
      for (int r = 0; r < 4; ++r)
        ub[(size_t)r * DD + n * 16] = acc[m][n][r];
  }
}

// ---------------- Phase 2: sequential scan h_t = tanh(U_t + Lam h_{t-1}) -----
// One block per batch row; 512 thr = 8 waves.
// Lane bit split: k-sublane s = bits{0,1,3} (8 chunks of 32 k);
// group g = bits{2,4,5}; G = wid*8+g owns rows [G*4, G*4+4).
// Reduce over s: xor1 (quad_perm) + xor2 (quad_perm) + xor8 (row_ror:8) —
// ALL on the VALU pipe; zero LDS ops in the reduction.
// h double-buffered in LDS, quad-XOR-swizzled; one barrier per step.
__global__ __launch_bounds__(512, 1) void rnn_scan(
    const float* __restrict__ Lm, float* outp /* U in, h out */)
{
  const int b = blockIdx.x;
  const int tid = threadIdx.x;
  const int wid = tid >> 6;
  const int lane = tid & 63;
  const int b0 = lane & 1, b1 = (lane >> 1) & 1, b3 = (lane >> 3) & 1;
  const int s = b0 | (b1 << 1) | (b3 << 2);
  const int s3 = s & 3;
  const int g = ((lane >> 2) & 1) | (((lane >> 4) & 3) << 1);
  const int G = (wid << 3) | g;
  const int jbase = G << 2;
  const int rmap = (b0 << 1) | b1;
  const int j_out = jbase + rmap;
  const bool wr = (b3 == 0);
  const bool s1b = (b0 != 0);
  const bool s2b = (b1 != 0);

  __shared__ __align__(16) __fp16 hbuf[2][DD];

  // weights: 4 rows x 16 f16x2 regs; k-chunk s*32
  half2_t lamw[4][16];
#pragma unroll
  for (int r = 0; r < 4; ++r) {
    const float* lp = Lm + (jbase + r) * DD + s * 32;
#pragma unroll
    for (int q = 0; q < 8; ++q) {
      float4 v = *(const float4*)(lp + q * 4);
      lamw[r][2 * q]     = __builtin_amdgcn_cvt_pkrtz(v.x, v.y);
      lamw[r][2 * q + 1] = __builtin_amdgcn_cvt_pkrtz(v.z, v.w);
    }
  }

  // h read: chunk s, quad slot (q ^ s3) holds original quad q (bank swizzle)
  const __fp16* hb0 = &hbuf[0][s * 32];
  const __fp16* hb1 = &hbuf[1][s * 32];
  const int o0 = 8 * (0 ^ s3), o1 = 8 * (1 ^ s3);
  const int o2 = 8 * (2 ^ s3), o3 = 8 * (3 ^ s3);
  // h write position for j_out under the same swizzle
  const int posj = (j_out & ~24) | ((((j_out >> 3) & 3) ^ ((j_out >> 5) & 3)) << 3);
  __fp16* hw0p = &hbuf[0][posj];
  __fp16* hw1p = &hbuf[1][posj];

  const size_t obase = (size_t)b * (TT * DD) + j_out;

  // prologue: h0 = 0 in hbuf[0]; U[0..3] register pipeline
  if (tid < 128) ((unsigned int*)hbuf)[tid] = 0u;
  float up0 = outp[obase + 0 * DD];
  float up1 = outp[obase + 1 * DD];
  float up2 = outp[obase + 2 * DD];
  float up3 = outp[obase + 3 * DD];
  __syncthreads();

  // Raw s_barrier + lgkmcnt-only drain: U prefetch loads / out stores stay in
  // flight across the barrier (vmcnt never drained in-loop).
#define STEP(t, up, p)                                                         \
  {                                                                            \
    const __fp16* hbp = (p) ? hb1 : hb0;                                       \
    uint4 hv0 = *(const uint4*)(hbp + o0);                                     \
    uint4 hv1 = *(const uint4*)(hbp + o1);                                     \
    uint4 hv2 = *(const uint4*)(hbp + o2);                                     \
    uint4 hv3 = *(const uint4*)(hbp + o3);                                     \
    unsigned int hw[16] = {hv0.x, hv0.y, hv0.z, hv0.w,                         \
                           hv1.x, hv1.y, hv1.z, hv1.w,                         \
                           hv2.x, hv2.y, hv2.z, hv2.w,                         \
                           hv3.x, hv3.y, hv3.z, hv3.w};                        \
    float accv[4];                                                             \
    _Pragma("unroll")                                                          \
    for (int r = 0; r < 4; ++r) {                                              \
      float A = 0.f, Bc = 0.f;                                                 \
      _Pragma("unroll")                                                        \
      for (int w2 = 0; w2 < 8; ++w2) {                                         \
        A  = fdot2(lamw[r][2 * w2],     __builtin_bit_cast(half2_t, hw[2 * w2]),     A);  \
        Bc = fdot2(lamw[r][2 * w2 + 1], __builtin_bit_cast(half2_t, hw[2 * w2 + 1]), Bc); \
      }                                                                        \
      accv[r] = A + Bc;                                                        \
    }                                                                          \
    /* stage 1 (xor1, DPP): b0=0 keeps rows {0,1}, b0=1 keeps {2,3} */         \
    float t0 = s1b ? accv[0] : accv[2], u0 = s1b ? accv[2] : accv[0];          \
    float t1 = s1b ? accv[1] : accv[3], u1 = s1b ? accv[3] : accv[1];          \
    float e0 = u0 + dpp_xor1(t0);                                              \
    float e1 = u1 + dpp_xor1(t1);                                              \
    /* stage 2 (xor2, DPP): keep row jbase + rmap */                           \
    float v0 = s2b ? e0 : e1, w0 = s2b ? e1 : e0;                              \
    float c0 = w0 + dpp_xor2(v0);                                              \
    /* stage 3 (xor8, DPP row_ror:8) + U + tanh */                             \
    float pre = c0 + dpp_xor8(c0) + (up);                                      \
    float hn = fast_tanh(pre);                                                 \
    if (wr) {                                                                  \
      outp[obase + (size_t)(t) * DD] = hn;                                     \
      *((p) ? hw0p : hw1p) = (__fp16)hn;  /* write parity p^1 */               \
    }                                                                          \
    { int tn = (t) + 4; tn = tn > TT - 1 ? TT - 1 : tn;                        \
      up = outp[obase + (size_t)tn * DD]; }                                    \
    asm volatile("s_waitcnt lgkmcnt(0)" ::: "memory");                         \
    __builtin_amdgcn_s_barrier();                                              \
    asm volatile("" ::: "memory");                                             \
  }

  for (int t = 0; t < TT; t += 4) {
    STEP(t + 0, up0, 0)
    STEP(t + 1, up1, 1)
    STEP(t + 2, up2, 0)
    STEP(t + 3, up3, 1)
  }
#undef STEP
}

extern "C" void kernel_launch(void* const* d_in, const int* in_sizes, int n_in,
                              void* d_out, int out_size, void* d_ws, size_t ws_size,
                              hipStream_t stream) {
  const float* X  = (const float*)d_in[0];   // [128, 2048, 256] f32
  const float* Bm = (const float*)d_in[1];   // [256, 256] f32
  const float* Lm = (const float*)d_in[2];   // [256, 256] f32
  float* out = (float*)d_out;                // [128, 2048, 256] f32

  (void)hipFuncSetAttribute((const void*)rnn_u_gemm,
                            hipFuncAttributeMaxDynamicSharedMemorySize,
                            256 * BST * 2);
  hipLaunchKernelGGL(rnn_u_gemm, dim3(2048), dim3(256), 256 * BST * 2, stream,
                     X, Bm, out);
  hipLaunchKernelGGL(rnn_scan, dim3(128), dim3(512), 0, stream, Lm, out);
}

// Round 7
// 1009.063 us; speedup vs baseline: 1.9444x; 1.1409x over previous
//
#include <hip/hip_runtime.h>

#define TT 2048
#define DD 256

typedef __fp16 half2_t __attribute__((ext_vector_type(2)));
typedef __fp16 half8_t __attribute__((ext_vector_type(8)));
typedef float f32x4_t __attribute__((ext_vector_type(4)));

static __device__ __forceinline__ float fdot2(half2_t a, half2_t b, float c) {
  return __builtin_amdgcn_fdot2(a, b, c, false);
}

static __device__ __forceinline__ float fast_tanh(float y) {
  float e = __builtin_amdgcn_exp2f(y * 2.885390081777927f);  // exp(2y)
  return 1.0f - 2.0f * __builtin_amdgcn_rcpf(e + 1.0f);
}

// All-DPP XOR-involution perms (VALU pipe). xor1/xor2/xor8 HW-validated by
// the passing R5 run; xor7 = row_half_mirror (lane ^ 7 within each 8).
static __device__ __forceinline__ float dpp_xor1(float v) {
  return __builtin_bit_cast(float, __builtin_amdgcn_update_dpp(
      0, __builtin_bit_cast(int, v), 0xB1 /*quad_perm 1,0,3,2*/, 0xF, 0xF, true));
}
static __device__ __forceinline__ float dpp_xor2(float v) {
  return __builtin_bit_cast(float, __builtin_amdgcn_update_dpp(
      0, __builtin_bit_cast(int, v), 0x4E /*quad_perm 2,3,0,1*/, 0xF, 0xF, true));
}
static __device__ __forceinline__ float dpp_xor7(float v) {
  return __builtin_bit_cast(float, __builtin_amdgcn_update_dpp(
      0, __builtin_bit_cast(int, v), 0x141 /*row_half_mirror*/, 0xF, 0xF, true));
}
static __device__ __forceinline__ float dpp_xor8(float v) {
  return __builtin_bit_cast(float, __builtin_amdgcn_update_dpp(
      0, __builtin_bit_cast(int, v), 0x128 /*row_ror:8*/, 0xF, 0xF, true));
}

// ---------------- Phase 1: U = X * B^T  (MFMA), U written into d_out ----------
#define BST 264
__global__ __launch_bounds__(256, 1) void rnn_u_gemm(
    const float* __restrict__ X, const float* __restrict__ Bm,
    float* __restrict__ U)
{
  extern __shared__ __fp16 bsh[];  // [256][BST]
  const int tid = threadIdx.x;

  {
    const float* br = Bm + tid * DD;
    __fp16* dst = bsh + tid * BST;
#pragma unroll
    for (int c = 0; c < 32; ++c) {
      float4 v0 = *(const float4*)(br + c * 8);
      float4 v1 = *(const float4*)(br + c * 8 + 4);
      uint4 w;
      w.x = __builtin_bit_cast(unsigned int, __builtin_amdgcn_cvt_pkrtz(v0.x, v0.y));
      w.y = __builtin_bit_cast(unsigned int, __builtin_amdgcn_cvt_pkrtz(v0.z, v0.w));
      w.z = __builtin_bit_cast(unsigned int, __builtin_amdgcn_cvt_pkrtz(v1.x, v1.y));
      w.w = __builtin_bit_cast(unsigned int, __builtin_amdgcn_cvt_pkrtz(v1.z, v1.w));
      *(uint4*)(dst + c * 8) = w;
    }
  }
  __syncthreads();

  const int wv = tid >> 6;
  const int l = tid & 63;
  const int l16 = l & 15;
  const int lk = l >> 4;
  const size_t tok0 = (size_t)blockIdx.x * 128 + wv * 32;

  f32x4_t acc[2][16];
#pragma unroll
  for (int m = 0; m < 2; ++m)
#pragma unroll
    for (int n = 0; n < 16; ++n)
      acc[m][n] = (f32x4_t){0.f, 0.f, 0.f, 0.f};

  const float* xA0 = X + (tok0 + l16) * DD + lk * 8;
  const float* xA1 = X + (tok0 + 16 + l16) * DD + lk * 8;

#pragma unroll
  for (int ks = 0; ks < 8; ++ks) {
    float4 a00 = *(const float4*)(xA0 + ks * 32);
    float4 a01 = *(const float4*)(xA0 + ks * 32 + 4);
    float4 a10 = *(const float4*)(xA1 + ks * 32);
    float4 a11 = *(const float4*)(xA1 + ks * 32 + 4);
    half2_t p0 = __builtin_amdgcn_cvt_pkrtz(a00.x, a00.y);
    half2_t p1 = __builtin_amdgcn_cvt_pkrtz(a00.z, a00.w);
    half2_t p2 = __builtin_amdgcn_cvt_pkrtz(a01.x, a01.y);
    half2_t p3 = __builtin_amdgcn_cvt_pkrtz(a01.z, a01.w);
    half2_t r0 = __builtin_amdgcn_cvt_pkrtz(a10.x, a10.y);
    half2_t r1 = __builtin_amdgcn_cvt_pkrtz(a10.z, a10.w);
    half2_t r2 = __builtin_amdgcn_cvt_pkrtz(a11.x, a11.y);
    half2_t r3 = __builtin_amdgcn_cvt_pkrtz(a11.z, a11.w);
    half8_t af0 = {p0[0], p0[1], p1[0], p1[1], p2[0], p2[1], p3[0], p3[1]};
    half8_t af1 = {r0[0], r0[1], r1[0], r1[1], r2[0], r2[1], r3[0], r3[1]};
#pragma unroll
    for (int n = 0; n < 16; ++n) {
      half8_t bf = *(const half8_t*)(bsh + (n * 16 + l16) * BST + ks * 32 + lk * 8);
      acc[0][n] = __builtin_amdgcn_mfma_f32_16x16x32_f16(af0, bf, acc[0][n], 0, 0, 0);
      acc[1][n] = __builtin_amdgcn_mfma_f32_16x16x32_f16(af1, bf, acc[1][n], 0, 0, 0);
    }
  }

#pragma unroll
  for (int m = 0; m < 2; ++m) {
    float* ub = U + (tok0 + m * 16 + lk * 4) * DD + l16;
#pragma unroll
    for (int n = 0; n < 16; ++n)
#pragma unroll
      for (int r = 0; r < 4; ++r)
        ub[(size_t)r * DD + n * 16] = acc[m][n][r];
  }
}

// ---------------- Phase 2: sequential scan h_t = tanh(U_t + Lam h_{t-1}) -----
// One block per batch row; 256 threads = 4 waves (1 wave/SIMD).
// Reduction lane-bits {b0,b1,b2,b3} (16-lane subspace), group bits {wid,b5,b4}:
//   G = wid*4 + b5*2 + b4 owns rows [G*16, G*16+16), J=16 rows/thread.
// Butterfly basis masks {1, 2, 7, 8} — all DPP involutions on the VALU pipe
// (xor7 = row_half_mirror; 7 is independent of {1,2,8} over GF(2)).
// Slot map: slot i holds row jbase + (i ^ rmap), rmap = L(lane) with
//   L(1)=8, L(2)=4, L(4)=14, L(8)=1  =>  rmap = b0*8 ^ b1*4 ^ b2*14 ^ b3.
// h LDS layout: h[j] at half-index ((j>>3)&1)*128 + (j>>4)*8 + (j&7):
//   per-thread read = 2x contiguous 16B (8 ds_read_b128/CU/step, 2-way banks).
// h write: partner row j_out^1 lives on lane^8 (L(8)=1) -> pn = dpp_xor8(hn),
//   b3==0 lanes write the packed even/odd f16 pair.
__global__ __launch_bounds__(256, 1) void rnn_scan(
    const float* __restrict__ Lm, float* outp /* U in, h out */)
{
  const int bb = blockIdx.x;
  const int tid = threadIdx.x;
  const int wid = tid >> 6;
  const int lane = tid & 63;
  const int b0 = lane & 1, b1 = (lane >> 1) & 1, b2 = (lane >> 2) & 1;
  const int b3 = (lane >> 3) & 1, b4 = (lane >> 4) & 1, b5 = (lane >> 5) & 1;
  const int s = lane & 15;                       // k-chunk [s*16, s*16+16)
  const int G = (wid << 2) | (b5 << 1) | b4;
  const int jbase = G << 4;
  const int rmap = (b0 << 3) ^ (b1 << 2) ^ (b2 ? 14 : 0) ^ b3;
  const int j_out = jbase + rmap;

  __shared__ __align__(16) __fp16 hbuf[2 * DD];  // 2 x 512 B, permuted layout

  // weights: slot i holds row jbase + (i ^ rmap), k-window [s*16, s*16+16)
  half2_t lamw[16][8];
#pragma unroll
  for (int i = 0; i < 16; ++i) {
    const float* lp = Lm + (jbase + (i ^ rmap)) * DD + s * 16;
#pragma unroll
    for (int c = 0; c < 4; ++c) {
      float4 v = *(const float4*)(lp + c * 4);
      lamw[i][2 * c]     = __builtin_amdgcn_cvt_pkrtz(v.x, v.y);
      lamw[i][2 * c + 1] = __builtin_amdgcn_cvt_pkrtz(v.z, v.w);
    }
  }

  const char* hrd = (const char*)hbuf + s * 16;
  // write byte addr of packed dword (j_out even, j_out^1) for b3==0 lanes:
  // j_out bits: hi4=G, bit3=b0^b2, bits2..0=(b1^b2, b2, 0)
  const int wbyte = ((b0 ^ b2) << 8) + (G << 4) + ((b1 ^ b2) << 3) + (b2 << 2);
  char* hwr = (char*)hbuf + wbyte;

  const size_t obase = (size_t)bb * (TT * DD) + j_out;

  if (tid < 128) ((unsigned int*)hbuf)[tid] = 0u;  // zero buf0 (512 B)
  float up0 = outp[obase + 0 * DD];
  float up1 = outp[obase + 1 * DD];
  float up2 = outp[obase + 2 * DD];
  float up3 = outp[obase + 3 * DD];
  __syncthreads();

  // Raw s_barrier + lgkmcnt-only drain: U prefetch loads / out stores stay in
  // flight across the barrier (vmcnt never drained in-loop).
#define STEP(t, up, p)                                                         \
  {                                                                            \
    uint4 hv0 = *(const uint4*)(hrd + (p) * 512);                              \
    uint4 hv1 = *(const uint4*)(hrd + (p) * 512 + 256);                        \
    unsigned int hd[8] = {hv0.x, hv0.y, hv0.z, hv0.w,                          \
                          hv1.x, hv1.y, hv1.z, hv1.w};                         \
    float acc[16];                                                             \
    _Pragma("unroll")                                                          \
    for (int i = 0; i < 16; ++i) {                                             \
      float a = 0.f;                                                           \
      _Pragma("unroll")                                                        \
      for (int q = 0; q < 8; ++q)                                              \
        a = fdot2(lamw[i][q], __builtin_bit_cast(half2_t, hd[q]), a);          \
      acc[i] = a;                                                              \
    }                                                                          \
    /* select-free butterfly; stage masks {1,2,7,8}, slot bits {8,4,2,1} */    \
    float r0 = acc[0] + dpp_xor1(acc[8]);                                      \
    float r1 = acc[1] + dpp_xor1(acc[9]);                                      \
    float r2 = acc[2] + dpp_xor1(acc[10]);                                     \
    float r3 = acc[3] + dpp_xor1(acc[11]);                                     \
    float r4 = acc[4] + dpp_xor1(acc[12]);                                     \
    float r5 = acc[5] + dpp_xor1(acc[13]);                                     \
    float r6 = acc[6] + dpp_xor1(acc[14]);                                     \
    float r7 = acc[7] + dpp_xor1(acc[15]);                                     \
    float s0 = r0 + dpp_xor2(r4);                                              \
    float s1 = r1 + dpp_xor2(r5);                                              \
    float s2 = r2 + dpp_xor2(r6);                                              \
    float s3 = r3 + dpp_xor2(r7);                                              \
    float t0 = s0 + dpp_xor7(s2);                                              \
    float t1 = s1 + dpp_xor7(s3);                                              \
    float pre = t0 + dpp_xor8(t1) + (up);                                      \
    float hn = fast_tanh(pre);                                                 \
    outp[obase + (size_t)(t) * DD] = hn;                                       \
    float pn = dpp_xor8(hn); /* partner row j_out^1 (L(8)=1) */                \
    if (b3 == 0) {                                                             \
      half2_t pk = __builtin_amdgcn_cvt_pkrtz(hn, pn);                         \
      *(unsigned int*)(hwr + ((p) ^ 1) * 512) =                                \
          __builtin_bit_cast(unsigned int, pk);                                \
    }                                                                          \
    { int tn = (t) + 4; tn = tn > TT - 1 ? TT - 1 : tn;                        \
      up = outp[obase + (size_t)tn * DD]; }                                    \
    asm volatile("s_waitcnt lgkmcnt(0)" ::: "memory");                         \
    __builtin_amdgcn_s_barrier();                                              \
    asm volatile("" ::: "memory");                                             \
  }

  for (int t = 0; t < TT; t += 4) {
    STEP(t + 0, up0, 0)
    STEP(t + 1, up1, 1)
    STEP(t + 2, up2, 0)
    STEP(t + 3, up3, 1)
  }
#undef STEP
}

extern "C" void kernel_launch(void* const* d_in, const int* in_sizes, int n_in,
                              void* d_out, int out_size, void* d_ws, size_t ws_size,
                              hipStream_t stream) {
  const float* X  = (const float*)d_in[0];   // [128, 2048, 256] f32
  const float* Bm = (const float*)d_in[1];   // [256, 256] f32
  const float* Lm = (const float*)d_in[2];   // [256, 256] f32
  float* out = (float*)d_out;                // [128, 2048, 256] f32

  (void)hipFuncSetAttribute((const void*)rnn_u_gemm,
                            hipFuncAttributeMaxDynamicSharedMemorySize,
                            256 * BST * 2);
  hipLaunchKernelGGL(rnn_u_gemm, dim3(2048), dim3(256), 256 * BST * 2, stream,
                     X, Bm, out);
  hipLaunchKernelGGL(rnn_scan, dim3(128), dim3(256), 0, stream, Lm, out);
}